// Round 8
// baseline (2761.568 us; speedup 1.0000x reference)
//
#include <hip/hip_runtime.h>
#include <math.h>

#define L_DIM 3072
#define B_DIM 64
#define H_DIM 256
#define HP2 260         // h-row stride (floats), 4-float aligned; all LDS patterns below are r4-proven shapes
#define TWO_PI_F 6.28318530717958647692f
#define EPS_F 1e-6f

__device__ __forceinline__ float mod2pi(float x){
    float q = floorf(x * (1.0f/TWO_PI_F));
    return fmaf(-TWO_PI_F, q, x);
}

// tanh(x) = 1 - 2/(e^{2x}+1); ~1e-7 abs err, exact saturation.
__device__ __forceinline__ float fast_tanh(float x){
    float t = __expf(2.0f*x);
    return 1.0f - __fdividef(2.0f, t + 1.0f);
}

// Wave-synchronous LDS fence: orders this wave's ds_writes before its later ds_reads
// (cross-LANE, same-wave). No __syncthreads needed for wave-private LDS tiles.
__device__ __forceinline__ void wave_lds_fence(){
    asm volatile("s_waitcnt lgkmcnt(0)" ::: "memory");
    __builtin_amdgcn_sched_barrier(0);
}

__global__ __launch_bounds__(256) void init_kernel(const float* __restrict__ zin, float* __restrict__ out){
    int i = blockIdx.x*256 + threadIdx.x;
    if (i < B_DIM*L_DIM) out[i] = zin[i];
    if (i < B_DIM) out[B_DIM*L_DIM + i] = 0.0f;   // zero ldj accumulators
}

// One coupling round, ZERO barriers. Each wave owns 16 sites end-to-end:
// stencil -> h1 -> (16 sites x 256 cols GEMM) -> h2 -> layer3 -> mixture epilogue.
// LDS: wave-private 16-row h tile. 4 waves/block, grid 1024, 2 blocks/CU -> 8
// independent waves/CU with no barrier convoys.
__global__ __launch_bounds__(256, 2) void round_kernel(
    float* __restrict__ z, float* __restrict__ ldj,
    const float* __restrict__ W1, const float* __restrict__ b1,
    const float* __restrict__ W2, const float* __restrict__ b2,
    const float* __restrict__ W3, const float* __restrict__ b3,
    int off)
{
    __shared__ float h_lds[64*HP2];       // 66560 B total; wave w owns rows [16w, 16w+16)

    const int tid  = threadIdx.x;
    const int lane = tid & 63;
    const int wv   = tid >> 6;            // wave id 0..3
    const int bid  = blockIdx.x;
    const int b    = bid >> 4;            // batch (16 blocks per batch)
    const int j0   = ((bid & 15) << 6) + wv*16;   // first site of THIS WAVE
    float* zb = z + b*L_DIM;
    float* hrow = &h_lds[(wv*16)*HP2];    // wave-private tile

    // -------- Phase A: stencil, computed redundantly in all 4 lane-groups --------
    // lane handles site j0 + (lane&15); groups 1..3 recompute the same values so
    // u/zr are already resident in every lane for the epilogue.
    const int sl = lane & 15;
    float c1v, c2v, uv, zrv;
    {
        int idx = 3*(j0 + sl) + off;
        int im2 = idx-2; if (im2 < 0) im2 += L_DIM;
        int im1 = idx-1; if (im1 < 0) im1 += L_DIM;
        int ip1 = idx+1; if (ip1 >= L_DIM) ip1 -= L_DIM;
        int ip2 = idx+2; if (ip2 >= L_DIM) ip2 -= L_DIM;
        float zi  = zb[idx];
        float zm1 = zb[im1];
        float zm2 = zb[im2];
        float zp1 = zb[ip1];
        float zp2 = zb[ip2];
        c1v = mod2pi(zm1 - zm2);          // V[idx-1]
        c2v = mod2pi(zp2 - zp1);          // V[idx+2]
        float V = mod2pi(zi - zm1);       // V[idx]
        float u = V * (1.0f/TWO_PI_F);
        uv  = fminf(fmaxf(u, EPS_F), 1.0f-EPS_F);
        zrv = zm1;
    }

    // -------- Phase B: h1[s][k] for the wave's 16 sites; lane covers k = 4*lane --------
    {
        const int k0 = lane*4;
        float4 w1a = *(const float4*)&W1[k0];
        float4 w1b = *(const float4*)&W1[H_DIM + k0];
        float4 b1v = *(const float4*)&b1[k0];
        #pragma unroll
        for (int s=0; s<16; s++){
            float c1s = __shfl(c1v, s, 64);   // site s's stencil from lane s
            float c2s = __shfl(c2v, s, 64);
            float4 o;
            o.x = fast_tanh(fmaf(c1s, w1a.x, fmaf(c2s, w1b.x, b1v.x)));
            o.y = fast_tanh(fmaf(c1s, w1a.y, fmaf(c2s, w1b.y, b1v.y)));
            o.z = fast_tanh(fmaf(c1s, w1a.z, fmaf(c2s, w1b.z, b1v.z)));
            o.w = fast_tanh(fmaf(c1s, w1a.w, fmaf(c2s, w1b.w, b1v.w)));
            *(float4*)&hrow[s*HP2 + k0] = o;  // contiguous b128 across lanes
        }
    }
    wave_lds_fence();

    // -------- Phase C: 16 sites x 256 cols GEMM, all within this wave --------
    const int ty = lane >> 4;             // 0..3 : site subgroup (sites 4sp+ty)
    const int tx = lane & 15;             // 0..15: col4 group
    float acc[4][4][4];                   // [sp][q][c]: site 4sp+ty, col q*64+tx*4+c
    #pragma unroll
    for (int sp=0; sp<4; sp++)
        #pragma unroll
        for (int q=0; q<4; q++)
            #pragma unroll
            for (int c=0; c<4; c++) acc[sp][q][c] = 0.f;

    const float4* __restrict__ W2v = (const float4*)W2;
    for (int k=0; k<H_DIM; k+=4){
        float a_[4][4];
        #pragma unroll
        for (int sp=0; sp<4; sp++){       // broadcast reads: 16 lanes (tx) share addr
            float4 t = *(const float4*)&hrow[(sp*4+ty)*HP2 + k];
            a_[sp][0]=t.x; a_[sp][1]=t.y; a_[sp][2]=t.z; a_[sp][3]=t.w;
        }
        #pragma unroll
        for (int j=0; j<4; j++){
            #pragma unroll
            for (int q=0; q<4; q++){
                float4 wq = W2v[(k+j)*64 + q*16 + tx];
                #pragma unroll
                for (int sp=0; sp<4; sp++){
                    acc[sp][q][0] = fmaf(a_[sp][j], wq.x, acc[sp][q][0]);
                    acc[sp][q][1] = fmaf(a_[sp][j], wq.y, acc[sp][q][1]);
                    acc[sp][q][2] = fmaf(a_[sp][j], wq.z, acc[sp][q][2]);
                    acc[sp][q][3] = fmaf(a_[sp][j], wq.w, acc[sp][q][3]);
                }
            }
        }
    }
    wave_lds_fence();     // drain C's reads before D overwrites the tile

    // -------- Phase D: h2 = tanh(acc + b2) back into the wave tile --------
    {
        #pragma unroll
        for (int q=0; q<4; q++){
            const int n0 = q*64 + tx*4;
            float4 bb = *(const float4*)&b2[n0];
            #pragma unroll
            for (int sp=0; sp<4; sp++){
                float4 o;
                o.x = fast_tanh(acc[sp][q][0] + bb.x);
                o.y = fast_tanh(acc[sp][q][1] + bb.y);
                o.z = fast_tanh(acc[sp][q][2] + bb.z);
                o.w = fast_tanh(acc[sp][q][3] + bb.w);
                *(float4*)&hrow[(sp*4+ty)*HP2 + n0] = o;   // r4-proven write shape
            }
        }
    }
    wave_lds_fence();

    // -------- Phase E: layer 3 for site (lane&15); lane-group ty owns param cols
    // {4ty..4ty+4} of each of the 3 sections (log_scale/shift/wlogit) --------
    float pls[4] = {0,0,0,0}, psh[4] = {0,0,0,0}, pwl[4] = {0,0,0,0};
    {
        const float* hE = &hrow[sl*HP2];  // 16 rows, 2 per bank-quad + broadcast = free
        for (int k=0; k<H_DIM; k+=4){
            float4 hv = *(const float4*)&hE[k];
            float hw[4] = {hv.x, hv.y, hv.z, hv.w};
            #pragma unroll
            for (int j=0; j<4; j++){
                const float* w3r = W3 + (k+j)*48;
                float4 qa = *(const float4*)&w3r[ty*4];
                float4 qb = *(const float4*)&w3r[16 + ty*4];
                float4 qc = *(const float4*)&w3r[32 + ty*4];
                float h = hw[j];
                pls[0]=fmaf(h,qa.x,pls[0]); pls[1]=fmaf(h,qa.y,pls[1]);
                pls[2]=fmaf(h,qa.z,pls[2]); pls[3]=fmaf(h,qa.w,pls[3]);
                psh[0]=fmaf(h,qb.x,psh[0]); psh[1]=fmaf(h,qb.y,psh[1]);
                psh[2]=fmaf(h,qb.z,psh[2]); psh[3]=fmaf(h,qb.w,psh[3]);
                pwl[0]=fmaf(h,qc.x,pwl[0]); pwl[1]=fmaf(h,qc.y,pwl[1]);
                pwl[2]=fmaf(h,qc.z,pwl[2]); pwl[3]=fmaf(h,qc.w,pwl[3]);
            }
        }
        float4 ba = *(const float4*)&b3[ty*4];
        float4 bbv= *(const float4*)&b3[16 + ty*4];
        float4 bc = *(const float4*)&b3[32 + ty*4];
        pls[0]+=ba.x; pls[1]+=ba.y; pls[2]+=ba.z; pls[3]+=ba.w;
        psh[0]+=bbv.x; psh[1]+=bbv.y; psh[2]+=bbv.z; psh[3]+=bbv.w;
        pwl[0]+=bc.x; pwl[1]+=bc.y; pwl[2]+=bc.z; pwl[3]+=bc.w;
    }

    // -------- Phase F: mixture epilogue, 4 lanes per site, shfl_xor reductions --------
    float ll = 0.0f;
    {
        // softmax over 16 wlogits (4 per lane, groups at xor 16/32)
        float mx = fmaxf(fmaxf(pwl[0],pwl[1]), fmaxf(pwl[2],pwl[3]));
        mx = fmaxf(mx, __shfl_xor(mx, 16, 64));
        mx = fmaxf(mx, __shfl_xor(mx, 32, 64));
        float e0 = __expf(pwl[0]-mx), e1 = __expf(pwl[1]-mx);
        float e2 = __expf(pwl[2]-mx), e3 = __expf(pwl[3]-mx);
        float se = e0+e1+e2+e3;
        se += __shfl_xor(se, 16, 64);
        se += __shfl_xor(se, 32, 64);
        float inv = __fdividef(0.84f, se);

        float u = uv;
        float a  = u*u;
        float om = 1.0f - u;
        float b_ = om*om;
        float apb = a + b_;
        float s = __fdividef(a, apb);
        float ds_du = __fdividef(2.0f*u*om, apb*apb);
        s = fminf(fmaxf(s, EPS_F), 1.0f-EPS_F);
        float logit_s = __logf(s) - log1pf(-s);

        float y = 0.0f, dd = 0.0f;
        float ee[4] = {e0,e1,e2,e3};
        #pragma unroll
        for (int i=0; i<4; i++){
            float alpha = __expf(pls[i]);
            float wgt = fmaf(ee[i], inv, 0.01f);
            float targ = alpha * (logit_s + psh[i]);
            float g = __fdividef(1.0f, 1.0f + __expf(-targ));
            y  = fmaf(wgt, g, y);
            dd = fmaf(wgt*alpha, g*(1.0f-g), dd);
        }
        y  += __shfl_xor(y, 16, 64);  y  += __shfl_xor(y, 32, 64);
        dd += __shfl_xor(dd, 16, 64); dd += __shfl_xor(dd, 32, 64);

        float dy_du = __fdividef(dd, s*(1.0f-s)) * ds_du;
        float llv = __logf(dy_du);

        if (ty == 0){                    // lanes 0..15: one writer per site
            ll = llv;
            int idx = 3*(j0 + sl) + off;
            zb[idx] = mod2pi(fmaf(TWO_PI_F, y, zrv));
        }
    }
    // wave butterfly reduction of ll, one atomic per wave
    #pragma unroll
    for (int o=32; o>0; o>>=1) ll += __shfl_down(ll, o, 64);
    if (lane == 0) atomicAdd(&ldj[b], ll);
}

extern "C" void kernel_launch(void* const* d_in, const int* in_sizes, int n_in,
                              void* d_out, int out_size, void* d_ws, size_t ws_size,
                              hipStream_t stream) {
    const float* z_in = (const float*)d_in[0];
    const float* W1 = (const float*)d_in[1];
    const float* b1 = (const float*)d_in[2];
    const float* W2 = (const float*)d_in[3];
    const float* b2 = (const float*)d_in[4];
    const float* W3 = (const float*)d_in[5];
    const float* b3 = (const float*)d_in[6];
    float* out = (float*)d_out;
    float* zbuf = out;                    // z worked in-place in d_out
    float* ldj  = out + B_DIM*L_DIM;

    init_kernel<<<(B_DIM*L_DIM + 255)/256, 256, 0, stream>>>(z_in, out);

    for (int t=0; t<12; t++){
        int r = t % 3;
        int off = (r==0) ? 0 : ((r==1) ? 2 : 1);
        round_kernel<<<1024, 256, 0, stream>>>(
            zbuf, ldj,
            W1 + t*2*H_DIM, b1 + t*H_DIM,
            W2 + t*H_DIM*H_DIM, b2 + t*H_DIM,
            W3 + t*H_DIM*48, b3 + t*48,
            off);
    }
}

// Round 9
// 2504.366 us; speedup vs baseline: 1.1027x; 1.1027x over previous
//
#include <hip/hip_runtime.h>
#include <math.h>

#define L_DIM 3072
#define B_DIM 64
#define H_DIM 256
#define HP2 261         // ODD dword stride: per-lane-row ds_read_b32 -> banks (5*lane+k)%32, 2-way = free
#define PP 49           // p-tile stride: odd -> spread
#define TWO_PI_F 6.28318530717958647692f
#define EPS_F 1e-6f

__device__ __forceinline__ float mod2pi(float x){
    float q = floorf(x * (1.0f/TWO_PI_F));
    return fmaf(-TWO_PI_F, q, x);
}

// tanh(x) = 1 - 2/(e^{2x}+1); ~1e-7 abs err, exact saturation.
__device__ __forceinline__ float fast_tanh(float x){
    float t = __expf(2.0f*x);
    return 1.0f - __fdividef(2.0f, t + 1.0f);
}

__global__ __launch_bounds__(256) void init_kernel(const float* __restrict__ zin, float* __restrict__ out){
    int i = blockIdx.x*256 + threadIdx.x;
    if (i < B_DIM*L_DIM) out[i] = zin[i];
    if (i < B_DIM) out[B_DIM*L_DIM + i] = 0.0f;   // zero ldj accumulators
}

// One coupling round. 64 sites/block = 64 lanes (lane = site), 4 waves, grid 1024.
// Wave w owns output cols [64w, 64w+64). W2/W3 read via wave-uniform addresses ->
// s_load broadcasts (scalar cache; vL1 port stays idle). h tile accessed row-per-lane
// with ODD stride b32 (2-way, free). Port budget/CU/round: VALU ~95us, LDS ~10us,
// sMEM ~7us, vL1 ~2us -> VALU-bound.
__global__ __launch_bounds__(256, 2) void round_kernel(
    float* __restrict__ z, float* __restrict__ ldj,
    const float* __restrict__ W1, const float* __restrict__ b1,
    const float* __restrict__ W2, const float* __restrict__ b2,
    const float* __restrict__ W3, const float* __restrict__ b3,
    int off)
{
    __shared__ float h_lds[64*HP2];       // 66816 B: h1 tile, then h2
    __shared__ float p_lds[64*PP];        // 12544 B: params
    __shared__ float c1_l[64], c2_l[64], u_l[64], zr_l[64];   // 1024 B  (total 80384)

    const int tid  = threadIdx.x;
    const int lane = tid & 63;                                  // site id
    const int wv_u = __builtin_amdgcn_readfirstlane(tid >> 6);  // uniform wave id 0..3
    const int bid = blockIdx.x;
    const int b  = bid >> 4;              // batch (16 blocks per batch)
    const int j0 = (bid & 15) << 6;       // first site of block
    float* zb = z + b*L_DIM;

    // -------- Phase 0: stencil / context (one thread per site) --------
    if (tid < 64){
        int idx = 3*(j0 + tid) + off;
        int im2 = idx-2; if (im2 < 0) im2 += L_DIM;
        int im1 = idx-1; if (im1 < 0) im1 += L_DIM;
        int ip1 = idx+1; if (ip1 >= L_DIM) ip1 -= L_DIM;
        int ip2 = idx+2; if (ip2 >= L_DIM) ip2 -= L_DIM;
        float zi  = zb[idx];
        float zm1 = zb[im1];
        float zm2 = zb[im2];
        float zp1 = zb[ip1];
        float zp2 = zb[ip2];
        c1_l[tid] = mod2pi(zm1 - zm2);    // V[idx-1]
        c2_l[tid] = mod2pi(zp2 - zp1);    // V[idx+2]
        float V   = mod2pi(zi - zm1);     // V[idx]
        float u = V * (1.0f/TWO_PI_F);
        u_l[tid] = fminf(fmaxf(u, EPS_F), 1.0f-EPS_F);
        zr_l[tid] = zm1;
    }
    __syncthreads();

    // -------- Phase 1: h1[m][k] = tanh(c1*W1[0,k] + c2*W1[1,k] + b1[k]), k = tid --------
    // writes: banks (5m + k)%32 over 64-lane k-range -> 2-way, free
    {
        float w0 = W1[tid];
        float w1 = W1[H_DIM + tid];
        float bb = b1[tid];
        #pragma unroll 8
        for (int m=0; m<64; m++){
            float pre = fmaf(c1_l[m], w0, fmaf(c2_l[m], w1, bb));
            h_lds[m*HP2 + tid] = fast_tanh(pre);
        }
    }
    __syncthreads();

    // -------- Phase 2: acc[64 cols of this wave] = h1[lane][:] @ W2[:, slice] --------
    float acc[64];
    #pragma unroll
    for (int c=0; c<64; c++) acc[c] = 0.f;
    {
        const float* __restrict__ hme = &h_lds[lane*HP2];
        #pragma unroll 4
        for (int k=0; k<H_DIM; k++){
            float hk = hme[k];                                   // ds_read_b32, 2-way free
            const float4* __restrict__ wr = (const float4*)W2 + k*64 + wv_u*16;  // uniform -> s_load
            #pragma unroll
            for (int q=0; q<16; q++){
                float4 wq = wr[q];
                acc[q*4+0] = fmaf(hk, wq.x, acc[q*4+0]);
                acc[q*4+1] = fmaf(hk, wq.y, acc[q*4+1]);
                acc[q*4+2] = fmaf(hk, wq.z, acc[q*4+2]);
                acc[q*4+3] = fmaf(hk, wq.w, acc[q*4+3]);
            }
        }
    }
    __syncthreads();      // ALL waves' h1 reads done before h2 overwrites the tile

    // -------- Phase 3: h2 = tanh(acc + b2) into own row, wave's col slice --------
    {
        const int n0 = wv_u*64;
        float* dst = &h_lds[lane*HP2 + n0];
        #pragma unroll
        for (int q=0; q<16; q++){
            float4 bb = *(const float4*)&b2[n0 + q*4];           // uniform -> s_load
            dst[q*4+0] = fast_tanh(acc[q*4+0] + bb.x);           // b32 writes, 2-way free
            dst[q*4+1] = fast_tanh(acc[q*4+1] + bb.y);
            dst[q*4+2] = fast_tanh(acc[q*4+2] + bb.z);
            dst[q*4+3] = fast_tanh(acc[q*4+3] + bb.w);
        }
    }
    __syncthreads();

    // -------- Phase 4: params[lane][12*wv..12*wv+12] = h2[lane][:] @ W3 + b3 --------
    {
        float acc3[12];
        #pragma unroll
        for (int r=0; r<12; r++) acc3[r] = 0.f;
        const float* __restrict__ hme = &h_lds[lane*HP2];
        #pragma unroll 4
        for (int k=0; k<H_DIM; k++){
            float h = hme[k];                                    // b32, free
            const float4* __restrict__ q = (const float4*)W3 + k*12 + wv_u*3;  // uniform -> s_load
            float4 q0 = q[0], q1 = q[1], q2 = q[2];
            acc3[0] = fmaf(h, q0.x, acc3[0]);  acc3[1] = fmaf(h, q0.y, acc3[1]);
            acc3[2] = fmaf(h, q0.z, acc3[2]);  acc3[3] = fmaf(h, q0.w, acc3[3]);
            acc3[4] = fmaf(h, q1.x, acc3[4]);  acc3[5] = fmaf(h, q1.y, acc3[5]);
            acc3[6] = fmaf(h, q1.z, acc3[6]);  acc3[7] = fmaf(h, q1.w, acc3[7]);
            acc3[8] = fmaf(h, q2.x, acc3[8]);  acc3[9] = fmaf(h, q2.y, acc3[9]);
            acc3[10]= fmaf(h, q2.z, acc3[10]); acc3[11]= fmaf(h, q2.w, acc3[11]);
        }
        #pragma unroll
        for (int r=0; r<12; r++)
            p_lds[lane*PP + wv_u*12 + r] = acc3[r] + b3[wv_u*12 + r];   // banks 49l spread, free
    }
    __syncthreads();

    // -------- Phase 5: epilogue, one thread per site (wave 0) --------
    float ll = 0.0f;
    if (tid < 64){
        const float* p = p_lds + tid*PP;  // [0..15] log_scale, [16..31] shift, [32..47] wlogit
        float mx = p[32];
        #pragma unroll
        for (int i=1; i<16; i++) mx = fmaxf(mx, p[32+i]);
        float w[16]; float se = 0.0f;
        #pragma unroll
        for (int i=0; i<16; i++){ w[i] = __expf(p[32+i]-mx); se += w[i]; }
        float inv = __fdividef(0.84f, se);   // (1 - K*MIN_W)/sum

        float u = u_l[tid];
        float a  = u*u;
        float om = 1.0f - u;
        float b_ = om*om;
        float apb = a + b_;
        float s = __fdividef(a, apb);
        float ds_du = __fdividef(2.0f*u*om, apb*apb);
        s = fminf(fmaxf(s, EPS_F), 1.0f-EPS_F);
        float logit_s = __logf(s) - log1pf(-s);

        float y = 0.0f, dd = 0.0f;
        #pragma unroll
        for (int i=0; i<16; i++){
            float alpha = __expf(p[i]);
            float wgt = fmaf(w[i], inv, 0.01f);
            float targ = alpha * (logit_s + p[16+i]);
            float g = __fdividef(1.0f, 1.0f + __expf(-targ));
            y  = fmaf(wgt, g, y);
            dd = fmaf(wgt*alpha, g*(1.0f-g), dd);
        }
        float dy_du = __fdividef(dd, s*(1.0f-s)) * ds_du;
        ll = __logf(dy_du);

        int idx = 3*(j0 + tid) + off;
        zb[idx] = mod2pi(fmaf(TWO_PI_F, y, zr_l[tid]));
    }
    // wave-0 butterfly reduction of ll, one atomic per block
    if (tid < 64){
        #pragma unroll
        for (int o=32; o>0; o>>=1) ll += __shfl_down(ll, o, 64);
        if (tid == 0) atomicAdd(&ldj[b], ll);
    }
}

extern "C" void kernel_launch(void* const* d_in, const int* in_sizes, int n_in,
                              void* d_out, int out_size, void* d_ws, size_t ws_size,
                              hipStream_t stream) {
    const float* z_in = (const float*)d_in[0];
    const float* W1 = (const float*)d_in[1];
    const float* b1 = (const float*)d_in[2];
    const float* W2 = (const float*)d_in[3];
    const float* b2 = (const float*)d_in[4];
    const float* W3 = (const float*)d_in[5];
    const float* b3 = (const float*)d_in[6];
    float* out = (float*)d_out;
    float* zbuf = out;                    // z worked in-place in d_out
    float* ldj  = out + B_DIM*L_DIM;

    init_kernel<<<(B_DIM*L_DIM + 255)/256, 256, 0, stream>>>(z_in, out);

    for (int t=0; t<12; t++){
        int r = t % 3;
        int off = (r==0) ? 0 : ((r==1) ? 2 : 1);
        round_kernel<<<1024, 256, 0, stream>>>(
            zbuf, ldj,
            W1 + t*2*H_DIM, b1 + t*H_DIM,
            W2 + t*H_DIM*H_DIM, b2 + t*H_DIM,
            W3 + t*H_DIM*48, b3 + t*48,
            off);
    }
}